// Round 1
// baseline (626.096 us; speedup 1.0000x reference)
//
#include <hip/hip_runtime.h>
#include <hip/hip_bf16.h>

// ---------------------------------------------------------------------------
// LorentzMLR: logits = -arccosh(clip(x0*c0 - xf @ cs^T, 1+eps))
//   x:  (4096, 256) fp32       xf rows, x0[m] = sqrt(1+|xf_m|^2)
//   lt: (32000, 257) fp32      cs = lt[:,1:], c0[n] = sqrt(1+|cs_n|^2)
//   out:(4096, 32000) fp32
// Strategy: bf16 MFMA GEMM (K=256) + fused epilogue; norms in fp32.
// ---------------------------------------------------------------------------

#define M_ROWS   4096
#define N_COLS   32000
#define K_DIM    256
#define LT_LD    257

typedef __bf16 v8bf __attribute__((ext_vector_type(8)));
typedef float  v4f  __attribute__((ext_vector_type(4)));

// ws layout (bytes)
#define XB_OFF   0u
#define CB_OFF   2097152u            // 4096*256*2
#define X0_OFF   18481152u           // CB_OFF + 32000*256*2
#define C0_OFF   18497536u           // X0_OFF + 4096*4
#define WS_NEED  18625536u           // C0_OFF + 32000*4

// --------------------------- prep: bf16 convert + norms ---------------------
__global__ __launch_bounds__(256) void prep_kernel(
    const float* __restrict__ x, const float* __restrict__ lt,
    __hip_bfloat16* __restrict__ xb, __hip_bfloat16* __restrict__ cb,
    float* __restrict__ x0, float* __restrict__ c0) {
  int row  = blockIdx.x * 4 + (threadIdx.x >> 6);   // one wave per row
  int lane = threadIdx.x & 63;
  if (row >= M_ROWS + N_COLS) return;

  float v[4];
  float ss = 0.0f;
  if (row < M_ROWS) {
    const float* src = x + (size_t)row * K_DIM;
#pragma unroll
    for (int k = 0; k < 4; ++k) { v[k] = src[k * 64 + lane]; ss += v[k] * v[k]; }
  } else {
    int c = row - M_ROWS;
    const float* src = lt + (size_t)c * LT_LD + 1;
#pragma unroll
    for (int k = 0; k < 4; ++k) { v[k] = src[k * 64 + lane]; ss += v[k] * v[k]; }
  }
  // wave-64 reduction
#pragma unroll
  for (int off = 32; off > 0; off >>= 1) ss += __shfl_down(ss, off, 64);

  __hip_bfloat16* dst = (row < M_ROWS) ? (xb + (size_t)row * K_DIM)
                                       : (cb + (size_t)(row - M_ROWS) * K_DIM);
#pragma unroll
  for (int k = 0; k < 4; ++k) dst[k * 64 + lane] = __float2bfloat16(v[k]);

  if (lane == 0) {
    float n = sqrtf(1.0f + ss);
    if (row < M_ROWS) x0[row] = n; else c0[row - M_ROWS] = n;
  }
}

// --------------------------- MFMA GEMM + epilogue ---------------------------
// Block tile 128(M) x 128(N), 256 threads = 4 waves in 2x2, wave tile 64x64.
// K loop: 8 iters of BK=32. LDS padded: stride 40 bf16 (2-way read conflicts).
#define LDT 40

__global__ __launch_bounds__(256) void gemm_kernel(
    const unsigned short* __restrict__ xb, const unsigned short* __restrict__ cb,
    const float* __restrict__ x0, const float* __restrict__ c0,
    float* __restrict__ out) {
  __shared__ __attribute__((aligned(16))) unsigned short Al[128 * LDT];
  __shared__ __attribute__((aligned(16))) unsigned short Bl[128 * LDT];

  const int tid  = threadIdx.x;
  const int w    = tid >> 6;
  const int lane = tid & 63;
  const int wm   = (w >> 1) * 64;       // wave M offset in tile
  const int wn   = (w & 1) * 64;        // wave N offset in tile
  const int lrow = lane & 15;
  const int lk   = (lane >> 4) * 8;

  const int mbase = blockIdx.y * 128;
  const int nbase = blockIdx.x * 128;

  // staging: thread covers rows (srow, srow+64), k-chunk sk..sk+7
  const int srow = tid >> 2;
  const int sk   = (tid & 3) * 8;

  v4f acc[4][4];
#pragma unroll
  for (int i = 0; i < 4; ++i)
#pragma unroll
    for (int j = 0; j < 4; ++j) acc[i][j] = (v4f){0.f, 0.f, 0.f, 0.f};

#pragma unroll 1
  for (int ki = 0; ki < 8; ++ki) {
    const int kofs = ki * 32 + sk;
    uint4 a0 = *(const uint4*)(xb + (size_t)(mbase + srow)      * K_DIM + kofs);
    uint4 a1 = *(const uint4*)(xb + (size_t)(mbase + srow + 64) * K_DIM + kofs);
    uint4 b0 = *(const uint4*)(cb + (size_t)(nbase + srow)      * K_DIM + kofs);
    uint4 b1 = *(const uint4*)(cb + (size_t)(nbase + srow + 64) * K_DIM + kofs);
    if (ki) __syncthreads();            // previous iter's LDS reads done
    *(uint4*)(&Al[srow * LDT + sk])        = a0;
    *(uint4*)(&Al[(srow + 64) * LDT + sk]) = a1;
    *(uint4*)(&Bl[srow * LDT + sk])        = b0;
    *(uint4*)(&Bl[(srow + 64) * LDT + sk]) = b1;
    __syncthreads();

    v8bf af[4], bf[4];
#pragma unroll
    for (int i = 0; i < 4; ++i)
      af[i] = *(const v8bf*)(&Al[(wm + i * 16 + lrow) * LDT + lk]);
#pragma unroll
    for (int j = 0; j < 4; ++j)
      bf[j] = *(const v8bf*)(&Bl[(wn + j * 16 + lrow) * LDT + lk]);
#pragma unroll
    for (int i = 0; i < 4; ++i)
#pragma unroll
      for (int j = 0; j < 4; ++j)
        acc[i][j] = __builtin_amdgcn_mfma_f32_16x16x32_bf16(af[i], bf[j], acc[i][j], 0, 0, 0);
  }

  // epilogue: C/D layout col=lane&15, row=(lane>>4)*4+reg  [verified m89]
  const int mloc = mbase + wm + (lane >> 4) * 4;
  const int nloc = nbase + wn + lrow;
  float cv[4];
#pragma unroll
  for (int j = 0; j < 4; ++j) cv[j] = c0[nloc + j * 16];

#pragma unroll
  for (int i = 0; i < 4; ++i) {
#pragma unroll
    for (int r = 0; r < 4; ++r) {
      const int m = mloc + i * 16 + r;
      const float xn = x0[m];
#pragma unroll
      for (int j = 0; j < 4; ++j) {
        float inner = xn * cv[j] - acc[i][j][r];
        float vv = fmaxf(inner, 1.000001f);
        float u  = vv + sqrtf(vv * vv - 1.0f);
        out[(size_t)m * N_COLS + nloc + j * 16] = -__logf(u);
      }
    }
  }
}

// --------------------------- fallback (ws too small) ------------------------
__global__ __launch_bounds__(256) void naive_kernel(
    const float* __restrict__ x, const float* __restrict__ lt,
    float* __restrict__ out) {
  int n = blockIdx.x * 256 + threadIdx.x;
  int m = blockIdx.y;
  if (n >= N_COLS) return;
  const float* xr = x + (size_t)m * K_DIM;
  const float* cr = lt + (size_t)n * LT_LD + 1;
  float ssx = 0.f, ssc = 0.f, dot = 0.f;
  for (int k = 0; k < K_DIM; ++k) {
    float xv = xr[k], cv = cr[k];
    ssx += xv * xv; ssc += cv * cv; dot += xv * cv;
  }
  float inner = sqrtf(1.f + ssx) * sqrtf(1.f + ssc) - dot;
  float vv = fmaxf(inner, 1.000001f);
  out[(size_t)m * N_COLS + n] = -logf(vv + sqrtf(vv * vv - 1.f));
}

// ---------------------------------------------------------------------------
extern "C" void kernel_launch(void* const* d_in, const int* in_sizes, int n_in,
                              void* d_out, int out_size, void* d_ws, size_t ws_size,
                              hipStream_t stream) {
  const float* x  = (const float*)d_in[0];
  const float* lt = (const float*)d_in[1];
  float* out = (float*)d_out;

  if (ws_size >= (size_t)WS_NEED) {
    char* ws = (char*)d_ws;
    __hip_bfloat16* xb = (__hip_bfloat16*)(ws + XB_OFF);
    __hip_bfloat16* cb = (__hip_bfloat16*)(ws + CB_OFF);
    float* x0 = (float*)(ws + X0_OFF);
    float* c0 = (float*)(ws + C0_OFF);

    prep_kernel<<<(M_ROWS + N_COLS) / 4, 256, 0, stream>>>(x, lt, xb, cb, x0, c0);
    gemm_kernel<<<dim3(N_COLS / 128, M_ROWS / 128), 256, 0, stream>>>(
        (const unsigned short*)xb, (const unsigned short*)cb, x0, c0, out);
  } else {
    naive_kernel<<<dim3((N_COLS + 255) / 256, M_ROWS), 256, 0, stream>>>(x, lt, out);
  }
}